// Round 2
// baseline (226.917 us; speedup 1.0000x reference)
//
#include <hip/hip_runtime.h>
#include <cstdint>
#include <cstddef>

#define B_    8
#define N_    2048
#define FIN   128
#define FOUT  64
#define ALPHA 0.2f
#define LOG2E 1.4426950408889634f

typedef __attribute__((ext_vector_type(8))) _Float16 half8;
typedef __attribute__((ext_vector_type(4))) _Float16 half4;
typedef __attribute__((ext_vector_type(4))) float float4v;

// ---------------------------------------------------------------------------
// Kernel 0: W [128][64] fp32 -> WtG fp16, transposed [f][k], split hi/lo
// planes (error-compensated fp16: v = hi + lo exactly to fp32 precision).
// ---------------------------------------------------------------------------
__global__ __launch_bounds__(256) void k0_convW(
    const float* __restrict__ W, _Float16* __restrict__ WtG)
{
    int o = blockIdx.x * 256 + threadIdx.x;   // 0..8191, grid 32x256
    int f = o >> 7, k = o & 127;
    float v = W[k * FOUT + f];
    _Float16 hi = (_Float16)v;
    _Float16 lo = (_Float16)(v - (float)hi);
    WtG[o] = hi;                              // plane 0: hi
    WtG[FOUT * FIN + o] = lo;                 // plane 1: lo
}

// ---------------------------------------------------------------------------
// Kernel 1: wh = x @ W via MFMA 16x16x32 f16 with split-fp16 compensation
// (acc = ah*bh + ah*bl + al*bh -> fp32-level accuracy). Unchanged from R1.
// ---------------------------------------------------------------------------
__global__ __launch_bounds__(256, 2) void k1_wh(
    const float* __restrict__ x, const _Float16* __restrict__ WtG,
    const float* __restrict__ w2, _Float16* __restrict__ whT,
    float* __restrict__ s1, float* __restrict__ s2)
{
    __shared__ __attribute__((aligned(16))) _Float16 xth[32][136];
    __shared__ __attribute__((aligned(16))) _Float16 xtl[32][136];
    __shared__ float s1p[4][32];
    __shared__ float s2p[4][32];

    int t = threadIdx.x, lane = t & 63, w = t >> 6;
    int b = blockIdx.x >> 6;
    int r0 = (blockIdx.x & 63) << 5;          // 32 rows per block
    const float* xb = x + ((size_t)b * N_ + r0) * FIN;

    #pragma unroll
    for (int j = 0; j < 4; ++j) {
        int idx = t + j * 256;
        int row = idx >> 5;
        int k0 = (idx & 31) * 4;
        float4 v = ((const float4*)xb)[idx];
        float vv[4] = {v.x, v.y, v.z, v.w};
        half4 h, l;
        #pragma unroll
        for (int e = 0; e < 4; ++e) {
            _Float16 hi = (_Float16)vv[e];
            h[e] = hi;
            l[e] = (_Float16)(vv[e] - (float)hi);
        }
        *(half4*)&xth[row][k0] = h;
        *(half4*)&xtl[row][k0] = l;
    }
    __syncthreads();

    int l15 = lane & 15, quad = lane >> 4;
    int f0 = w * 16;

    half8 bh[4], bl[4];
    const _Float16* wgh = WtG + (f0 + l15) * FIN + quad * 8;
    #pragma unroll
    for (int c = 0; c < 4; ++c) {
        bh[c] = *(const half8*)(wgh + c * 32);
        bl[c] = *(const half8*)(wgh + FOUT * FIN + c * 32);
    }
    float a1f = w2[f0 + l15], a2f = w2[FOUT + f0 + l15];

    #pragma unroll
    for (int rt = 0; rt < 2; ++rt) {
        float4v acc = {0.f, 0.f, 0.f, 0.f};
        #pragma unroll
        for (int c = 0; c < 4; ++c) {
            half8 ah = *(const half8*)&xth[rt * 16 + l15][c * 32 + quad * 8];
            half8 al = *(const half8*)&xtl[rt * 16 + l15][c * 32 + quad * 8];
            acc = __builtin_amdgcn_mfma_f32_16x16x32_f16(ah, bh[c], acc, 0, 0, 0);
            acc = __builtin_amdgcn_mfma_f32_16x16x32_f16(ah, bl[c], acc, 0, 0, 0);
            acc = __builtin_amdgcn_mfma_f32_16x16x32_f16(al, bh[c], acc, 0, 0, 0);
        }
        half4 hv;
        #pragma unroll
        for (int reg = 0; reg < 4; ++reg) hv[reg] = (_Float16)acc[reg];
        *(half4*)(whT + ((size_t)b * FOUT + f0 + l15) * N_ + r0 + rt * 16 + quad * 4) = hv;

        #pragma unroll
        for (int reg = 0; reg < 4; ++reg) {
            float v1 = acc[reg] * a1f;
            float v2 = acc[reg] * a2f;
            #pragma unroll
            for (int m = 1; m <= 8; m <<= 1) {
                v1 += __shfl_xor(v1, m);
                v2 += __shfl_xor(v2, m);
            }
            if (l15 == 0) {
                s1p[w][rt * 16 + quad * 4 + reg] = v1;
                s2p[w][rt * 16 + quad * 4 + reg] = v2;
            }
        }
    }
    __syncthreads();
    if (t < 32) {
        float v = s1p[0][t] + s1p[1][t] + s1p[2][t] + s1p[3][t];
        s1[(size_t)b * N_ + r0 + t] = v;
    } else if (t < 64) {
        int r = t - 32;
        float v = s2p[0][r] + s2p[1][r] + s2p[2][r] + s2p[3][r];
        s2[(size_t)b * N_ + r0 + r] = v;
    }
}

// ---------------------------------------------------------------------------
// Kernel 2: producer/consumer wave-specialized flash attention.
// 512 threads: waves 0-3 = producers (4 rows each: adj->p->pT),
//              waves 4-7 = consumers (16 features each: pT x whT MFMA).
// Separate vmcnt streams: adj HBM latency never blocks bf L2 loads.
// Chunk=256, pT double-buffered, adj/s2 reg-prefetched 2 iterations ahead.
// Barriers count-matched across the wave-uniform divergent paths:
// 1 (smax) + 1 (prologue) + 8 (loop) on both sides.
// pT stride 264 fp16: consumer A-read lane (l15,quad) -> bank group
// 4*(l15+quad) mod 32 = structural-min, conflict-free; 16B-aligned.
// ---------------------------------------------------------------------------
__global__ __launch_bounds__(512, 4) void k2_attn(
    const int* __restrict__ adj, const _Float16* __restrict__ whT,
    const float* __restrict__ s1, const float* __restrict__ s2,
    float* __restrict__ out)
{
    __shared__ __attribute__((aligned(16))) _Float16 pT[2][16][264];
    __shared__ float lL[16];
    __shared__ float smaxL[8];

    int t = threadIdx.x, lane = t & 63, w = t >> 6;
    int b = blockIdx.x >> 7;
    int i0 = (blockIdx.x & 127) << 4;

    // --- exact S2MAX over batch b (8 KB, L2-hot); 512 threads x 1 float4 ---
    const float4* s2v = (const float4*)(s2 + (size_t)b * N_);
    float4 uv = s2v[t];
    float vm = fmaxf(fmaxf(uv.x, uv.y), fmaxf(uv.z, uv.w));
    #pragma unroll
    for (int m = 32; m >= 1; m >>= 1) vm = fmaxf(vm, __shfl_xor(vm, m));
    if (lane == 0) smaxL[w] = vm;
    __syncthreads();                                   // barrier #1 (shared)

    int l15 = lane & 15, quad = lane >> 4;

    if (w < 4) {
        // ======================= PRODUCER =======================
        float s2max = smaxL[0];
        #pragma unroll
        for (int i = 1; i < 8; ++i) s2max = fmaxf(s2max, smaxL[i]);

        float c1[4], c2[4], lacc[4];
        #pragma unroll
        for (int rr = 0; rr < 4; ++rr) {
            float sv = s1[(size_t)b * N_ + i0 + w * 4 + rr];  // wave-uniform
            float mm = sv + s2max;
            float mh = fmaxf(mm, ALPHA * mm);   // leaky(s1_i + s2max) >= row max
            c1[rr] = (sv - mh) * LOG2E;
            c2[rr] = (ALPHA * sv - mh) * LOG2E;
            lacc[rr] = 0.f;
        }

        const int* adjB = adj + ((size_t)b * N_ + i0 + w * 4) * N_ + lane * 4;
        const float* s2B = s2 + (size_t)b * N_ + lane * 4;

        int4  Ab[2][4];   // adj prefetch, 2 chunks in flight
        float4 Sb[2];     // s2 prefetch

        // prologue: prefetch chunks 0 and 1
        #pragma unroll
        for (int j = 0; j < 2; ++j) {
            Sb[j] = *(const float4*)(s2B + j * 256);
            #pragma unroll
            for (int rr = 0; rr < 4; ++rr)
                Ab[j][rr] = *(const int4*)(adjB + (size_t)rr * N_ + j * 256);
        }

        // computeP(chunk 0) -> pT[0]
        {
            float4 sv = Sb[0];
            float u[4]  = {sv.x * LOG2E, sv.y * LOG2E, sv.z * LOG2E, sv.w * LOG2E};
            float ua[4] = {u[0] * ALPHA, u[1] * ALPHA, u[2] * ALPHA, u[3] * ALPHA};
            #pragma unroll
            for (int rr = 0; rr < 4; ++rr) {
                int aa[4] = {Ab[0][rr].x, Ab[0][rr].y, Ab[0][rr].z, Ab[0][rr].w};
                half4 pf;
                float ls = 0.f;
                #pragma unroll
                for (int e = 0; e < 4; ++e) {
                    float tt = fmaxf(c1[rr] + u[e], c2[rr] + ua[e]);
#if __has_builtin(__builtin_amdgcn_exp2f)
                    float p = __builtin_amdgcn_exp2f(tt);
#else
                    float p = exp2f(tt);
#endif
                    p = (aa[e] > 0) ? p : 0.f;
                    ls += p;
                    pf[e] = (_Float16)p;
                }
                lacc[rr] += ls;
                *(half4*)&pT[0][w * 4 + rr][lane * 4] = pf;
            }
        }
        __syncthreads();                               // barrier #2

        #pragma unroll
        for (int c = 0; c < 8; ++c) {
            // issue prefetch for chunk c+2 (lands ~2 iterations later)
            if (c < 6) {
                Sb[c & 1] = *(const float4*)(s2B + (c + 2) * 256);
                #pragma unroll
                for (int rr = 0; rr < 4; ++rr)
                    Ab[c & 1][rr] = *(const int4*)(adjB + (size_t)rr * N_ + (c + 2) * 256);
            }
            // compute p for chunk c+1 into pT[(c+1)&1]
            if (c < 7) {
                float4 sv = Sb[(c + 1) & 1];
                float u[4]  = {sv.x * LOG2E, sv.y * LOG2E, sv.z * LOG2E, sv.w * LOG2E};
                float ua[4] = {u[0] * ALPHA, u[1] * ALPHA, u[2] * ALPHA, u[3] * ALPHA};
                #pragma unroll
                for (int rr = 0; rr < 4; ++rr) {
                    int4 av = Ab[(c + 1) & 1][rr];
                    int aa[4] = {av.x, av.y, av.z, av.w};
                    half4 pf;
                    float ls = 0.f;
                    #pragma unroll
                    for (int e = 0; e < 4; ++e) {
                        float tt = fmaxf(c1[rr] + u[e], c2[rr] + ua[e]);
#if __has_builtin(__builtin_amdgcn_exp2f)
                        float p = __builtin_amdgcn_exp2f(tt);
#else
                        float p = exp2f(tt);
#endif
                        p = (aa[e] > 0) ? p : 0.f;
                        ls += p;
                        pf[e] = (_Float16)p;
                    }
                    lacc[rr] += ls;
                    *(half4*)&pT[(c + 1) & 1][w * 4 + rr][lane * 4] = pf;
                }
                if (c == 6) {
                    // all 8 chunks accumulated -> publish row sums
                    #pragma unroll
                    for (int rr = 0; rr < 4; ++rr) {
                        float v = lacc[rr];
                        #pragma unroll
                        for (int m = 32; m >= 1; m >>= 1) v += __shfl_xor(v, m);
                        if (lane == 0) lL[w * 4 + rr] = v;
                    }
                }
            }
            __syncthreads();                           // barriers #3..#10
        }
        // producers done
    } else {
        // ======================= CONSUMER =======================
        int f0 = (w - 4) * 16;
        float4v acc = {0.f, 0.f, 0.f, 0.f};
        const _Float16* wB = whT + ((size_t)b * FOUT + f0 + l15) * N_ + quad * 8;

        __syncthreads();                               // barrier #2 (match prologue)

        #pragma unroll
        for (int c = 0; c < 8; ++c) {
            const _Float16* wp = wB + c * 256;
            __builtin_amdgcn_s_setprio(1);
            #pragma unroll
            for (int kk = 0; kk < 8; ++kk) {
                half8 af = *(const half8*)&pT[c & 1][l15][kk * 32 + quad * 8];
                half8 bf = *(const half8*)(wp + kk * 32);
                acc = __builtin_amdgcn_mfma_f32_16x16x32_f16(af, bf, acc, 0, 0, 0);
            }
            __builtin_amdgcn_s_setprio(0);
            __syncthreads();                           // barriers #3..#10
        }

        // epilogue: normalize, ELU, store. D: row=quad*4+reg, col=f0+l15
        #pragma unroll
        for (int reg = 0; reg < 4; ++reg) {
            int row = quad * 4 + reg;
            float val = acc[reg] / lL[row];
            val = (val > 0.f) ? val : (__expf(val) - 1.f);   // ELU
            out[((size_t)b * N_ + i0 + row) * FOUT + f0 + l15] = val;
        }
    }
}

// ---------------------------------------------------------------------------
extern "C" void kernel_launch(void* const* d_in, const int* in_sizes, int n_in,
                              void* d_out, int out_size, void* d_ws, size_t ws_size,
                              hipStream_t stream) {
    const float* x   = (const float*)d_in[0];
    const int*   adj = (const int*)d_in[1];
    const float* W   = (const float*)d_in[2];
    const float* w2  = (const float*)d_in[3];
    float* out = (float*)d_out;

    _Float16* whT = (_Float16*)d_ws;                                  // 2 MiB
    float* s1 = (float*)((char*)d_ws + (size_t)B_ * FOUT * N_ * 2);   // 64 KiB
    float* s2 = s1 + (size_t)B_ * N_;                                 // 64 KiB
    _Float16* WtG = (_Float16*)(s2 + (size_t)B_ * N_);                // 32 KiB (hi+lo)

    k0_convW<<<32, 256, 0, stream>>>(W, WtG);
    k1_wh<<<(B_ * N_) / 32, 256, 0, stream>>>(x, WtG, w2, whT, s1, s2);
    k2_attn<<<(B_ * N_) / 16, 512, 0, stream>>>(adj, whT, s1, s2, out);
}

// Round 3
// 214.005 us; speedup vs baseline: 1.0603x; 1.0603x over previous
//
#include <hip/hip_runtime.h>
#include <cstdint>
#include <cstddef>

#define B_    8
#define N_    2048
#define FIN   128
#define FOUT  64
#define ALPHA 0.2f
#define LOG2E 1.4426950408889634f

typedef __attribute__((ext_vector_type(8))) _Float16 half8;
typedef __attribute__((ext_vector_type(4))) _Float16 half4;
typedef __attribute__((ext_vector_type(4))) float float4v;

// ---------------------------------------------------------------------------
// Kernel 0: W [128][64] fp32 -> WtG fp16, transposed [f][k], split hi/lo
// planes (error-compensated fp16: v = hi + lo exactly to fp32 precision).
// ---------------------------------------------------------------------------
__global__ __launch_bounds__(256) void k0_convW(
    const float* __restrict__ W, _Float16* __restrict__ WtG)
{
    int o = blockIdx.x * 256 + threadIdx.x;   // 0..8191, grid 32x256
    int f = o >> 7, k = o & 127;
    float v = W[k * FOUT + f];
    _Float16 hi = (_Float16)v;
    _Float16 lo = (_Float16)(v - (float)hi);
    WtG[o] = hi;                              // plane 0: hi
    WtG[FOUT * FIN + o] = lo;                 // plane 1: lo
}

// ---------------------------------------------------------------------------
// Kernel 1: wh = x @ W via MFMA 16x16x32 f16 with split-fp16 compensation
// (acc = ah*bh + ah*bl + al*bh -> fp32-level accuracy). Unchanged.
// ---------------------------------------------------------------------------
__global__ __launch_bounds__(256, 2) void k1_wh(
    const float* __restrict__ x, const _Float16* __restrict__ WtG,
    const float* __restrict__ w2, _Float16* __restrict__ whT,
    float* __restrict__ s1, float* __restrict__ s2)
{
    __shared__ __attribute__((aligned(16))) _Float16 xth[32][136];
    __shared__ __attribute__((aligned(16))) _Float16 xtl[32][136];
    __shared__ float s1p[4][32];
    __shared__ float s2p[4][32];

    int t = threadIdx.x, lane = t & 63, w = t >> 6;
    int b = blockIdx.x >> 6;
    int r0 = (blockIdx.x & 63) << 5;          // 32 rows per block
    const float* xb = x + ((size_t)b * N_ + r0) * FIN;

    #pragma unroll
    for (int j = 0; j < 4; ++j) {
        int idx = t + j * 256;
        int row = idx >> 5;
        int k0 = (idx & 31) * 4;
        float4 v = ((const float4*)xb)[idx];
        float vv[4] = {v.x, v.y, v.z, v.w};
        half4 h, l;
        #pragma unroll
        for (int e = 0; e < 4; ++e) {
            _Float16 hi = (_Float16)vv[e];
            h[e] = hi;
            l[e] = (_Float16)(vv[e] - (float)hi);
        }
        *(half4*)&xth[row][k0] = h;
        *(half4*)&xtl[row][k0] = l;
    }
    __syncthreads();

    int l15 = lane & 15, quad = lane >> 4;
    int f0 = w * 16;

    half8 bh[4], bl[4];
    const _Float16* wgh = WtG + (f0 + l15) * FIN + quad * 8;
    #pragma unroll
    for (int c = 0; c < 4; ++c) {
        bh[c] = *(const half8*)(wgh + c * 32);
        bl[c] = *(const half8*)(wgh + FOUT * FIN + c * 32);
    }
    float a1f = w2[f0 + l15], a2f = w2[FOUT + f0 + l15];

    #pragma unroll
    for (int rt = 0; rt < 2; ++rt) {
        float4v acc = {0.f, 0.f, 0.f, 0.f};
        #pragma unroll
        for (int c = 0; c < 4; ++c) {
            half8 ah = *(const half8*)&xth[rt * 16 + l15][c * 32 + quad * 8];
            half8 al = *(const half8*)&xtl[rt * 16 + l15][c * 32 + quad * 8];
            acc = __builtin_amdgcn_mfma_f32_16x16x32_f16(ah, bh[c], acc, 0, 0, 0);
            acc = __builtin_amdgcn_mfma_f32_16x16x32_f16(ah, bl[c], acc, 0, 0, 0);
            acc = __builtin_amdgcn_mfma_f32_16x16x32_f16(al, bh[c], acc, 0, 0, 0);
        }
        half4 hv;
        #pragma unroll
        for (int reg = 0; reg < 4; ++reg) hv[reg] = (_Float16)acc[reg];
        *(half4*)(whT + ((size_t)b * FOUT + f0 + l15) * N_ + r0 + rt * 16 + quad * 4) = hv;

        #pragma unroll
        for (int reg = 0; reg < 4; ++reg) {
            float v1 = acc[reg] * a1f;
            float v2 = acc[reg] * a2f;
            #pragma unroll
            for (int m = 1; m <= 8; m <<= 1) {
                v1 += __shfl_xor(v1, m);
                v2 += __shfl_xor(v2, m);
            }
            if (l15 == 0) {
                s1p[w][rt * 16 + quad * 4 + reg] = v1;
                s2p[w][rt * 16 + quad * 4 + reg] = v2;
            }
        }
    }
    __syncthreads();
    if (t < 32) {
        float v = s1p[0][t] + s1p[1][t] + s1p[2][t] + s1p[3][t];
        s1[(size_t)b * N_ + r0 + t] = v;
    } else if (t < 64) {
        int r = t - 32;
        float v = s2p[0][r] + s2p[1][r] + s2p[2][r] + s2p[3][r];
        s2[(size_t)b * N_ + r0 + r] = v;
    }
}

// ---------------------------------------------------------------------------
// Kernel 2: flash-style masked softmax + PV, adj staged via global_load_lds
// DMA (in-flight bytes live in the LDS queue, not VGPRs -> no 1.4 TB/s cap).
// 256 thr / 4 waves / 16 rows / chunk 256 / 8 iters.
// Per iter: bf(c)->regs (L2), STAGE(c+1) DMA, counted vmcnt(13) (drain only
// chunk c's DMA; bf + next stage stay in flight), p-compute(c)->pT[c&1],
// ONE barrier (pT double-buffered), MFMA(c).
// Each wave DMAs and reads ONLY its own 4 rows of adjS -> per-wave vmcnt is
// sufficient ordering for adjS; pT handoff uses the barrier.
// pT stride 264: MFMA A-read bank group 4*(l15+quad) mod 32 = structural min.
// ---------------------------------------------------------------------------
__global__ __launch_bounds__(256, 4) void k2_attn(
    const int* __restrict__ adj, const _Float16* __restrict__ whT,
    const float* __restrict__ s1, const float* __restrict__ s2,
    float* __restrict__ out)
{
    __shared__ __attribute__((aligned(16))) int adjS[2][16][256];       // 32 KB
    __shared__ __attribute__((aligned(16))) _Float16 pT[2][16][264];    // 16.5 KB
    __shared__ float lL[16];
    __shared__ float smaxL[4];

    int t = threadIdx.x, lane = t & 63, w = t >> 6;
    int b = blockIdx.x >> 7;
    int i0 = (blockIdx.x & 127) << 4;

    // --- exact S2MAX over batch b (8 KB, L2-hot) ---
    const float4* s2v = (const float4*)(s2 + (size_t)b * N_);
    float4 ua_ = s2v[t], ub_ = s2v[t + 256];
    float vm = fmaxf(fmaxf(fmaxf(ua_.x, ua_.y), fmaxf(ua_.z, ua_.w)),
                     fmaxf(fmaxf(ub_.x, ub_.y), fmaxf(ub_.z, ub_.w)));
    #pragma unroll
    for (int m = 32; m >= 1; m >>= 1) vm = fmaxf(vm, __shfl_xor(vm, m));
    if (lane == 0) smaxL[w] = vm;
    __syncthreads();
    float s2max = fmaxf(fmaxf(smaxL[0], smaxL[1]), fmaxf(smaxL[2], smaxL[3]));

    int l15 = lane & 15, quad = lane >> 4;
    int f0 = w * 16;

    // per-row folded constants (wave w owns rows w*4..w*4+3)
    float c1[4], c2[4], lacc[4];
    #pragma unroll
    for (int rr = 0; rr < 4; ++rr) {
        float sv = s1[(size_t)b * N_ + i0 + w * 4 + rr];   // wave-uniform
        float mm = sv + s2max;
        float mh = fmaxf(mm, ALPHA * mm);    // leaky(s1_i + s2max) >= row max
        c1[rr] = (sv - mh) * LOG2E;
        c2[rr] = (ALPHA * sv - mh) * LOG2E;
        lacc[rr] = 0.f;
    }

    // per-lane global bases
    const int* adjL = adj + ((size_t)b * N_ + i0 + w * 4) * N_ + lane * 4;
    const float* s2L = s2 + (size_t)b * N_ + lane * 4;
    float4 Sb[2];

    // DMA one chunk's 4 rows (this wave's rows) + s2 reg prefetch. 5 vm ops.
#define STAGE(cn, bf) do {                                                   \
        _Pragma("unroll")                                                    \
        for (int rr = 0; rr < 4; ++rr) {                                     \
            const int* src_ = adjL + (size_t)rr * N_ + (cn) * 256;           \
            __builtin_amdgcn_global_load_lds(                                \
                (const __attribute__((address_space(1))) void*)src_,         \
                (__attribute__((address_space(3))) void*)&adjS[bf][w * 4 + rr][0], \
                16, 0, 0);                                                   \
        }                                                                    \
        Sb[bf] = *(const float4*)(s2L + (cn) * 256);                         \
    } while (0)

    STAGE(0, 0);                              // prologue: chunk 0 in flight

    float4v acc = {0.f, 0.f, 0.f, 0.f};
    const _Float16* wB = whT + ((size_t)b * FOUT + f0 + l15) * N_ + quad * 8;

    #pragma unroll
    for (int c = 0; c < 8; ++c) {
        // bf(c) into regs FIRST (older than the new stage -> compiler's
        // bf-waits never force the fresh DMA to drain)
        half8 bfr[8];
        const _Float16* wp = wB + c * 256;
        #pragma unroll
        for (int kk = 0; kk < 8; ++kk) bfr[kk] = *(const half8*)(wp + kk * 32);

        if (c < 7) {
            STAGE(c + 1, (c + 1) & 1);
            asm volatile("s_waitcnt vmcnt(13)" ::: "memory"); // drain chunk c DMA only
        } else {
            asm volatile("s_waitcnt vmcnt(8)" ::: "memory");  // leave bf(7) in flight
        }
        __builtin_amdgcn_sched_barrier(0);

        // p-compute chunk c from adjS[c&1] + Sb[c&1]
        {
            float4 sv = Sb[c & 1];
            float u[4]  = {sv.x * LOG2E, sv.y * LOG2E, sv.z * LOG2E, sv.w * LOG2E};
            float ua[4] = {u[0] * ALPHA, u[1] * ALPHA, u[2] * ALPHA, u[3] * ALPHA};
            #pragma unroll
            for (int rr = 0; rr < 4; ++rr) {
                int r = w * 4 + rr;
                int4 av = *(const int4*)&adjS[c & 1][r][lane * 4];
                int aa[4] = {av.x, av.y, av.z, av.w};
                half4 pf;
                float ls = 0.f;
                #pragma unroll
                for (int e = 0; e < 4; ++e) {
                    float tt = fmaxf(c1[rr] + u[e], c2[rr] + ua[e]);
#if __has_builtin(__builtin_amdgcn_exp2f)
                    float p = __builtin_amdgcn_exp2f(tt);
#else
                    float p = exp2f(tt);
#endif
                    p = (aa[e] > 0) ? p : 0.f;
                    ls += p;
                    pf[e] = (_Float16)p;
                }
                lacc[rr] += ls;
                *(half4*)&pT[c & 1][r][lane * 4] = pf;
            }
        }

        if (c == 7) {
            // publish row sums before the last barrier
            #pragma unroll
            for (int rr = 0; rr < 4; ++rr) {
                float v = lacc[rr];
                #pragma unroll
                for (int m = 32; m >= 1; m >>= 1) v += __shfl_xor(v, m);
                if (lane == 0) lL[w * 4 + rr] = v;
            }
        }

        __syncthreads();   // publish pT[c&1]; also proves pT[(c)&1^1] readers done

        // MFMA on pT[c&1] with reg-resident B
        #pragma unroll
        for (int kk = 0; kk < 8; ++kk) {
            half8 af = *(const half8*)&pT[c & 1][l15][kk * 32 + quad * 8];
            acc = __builtin_amdgcn_mfma_f32_16x16x32_f16(af, bfr[kk], acc, 0, 0, 0);
        }
        // no second barrier: next iter writes the other pT buffer; the next
        // barrier proves all waves finished this MFMA before buffer reuse.
    }
#undef STAGE

    // epilogue: normalize, ELU, store. D: row=quad*4+reg, col=f0+l15
    #pragma unroll
    for (int reg = 0; reg < 4; ++reg) {
        int row = quad * 4 + reg;
        float val = acc[reg] / lL[row];
        val = (val > 0.f) ? val : (__expf(val) - 1.f);   // ELU
        out[((size_t)b * N_ + i0 + row) * FOUT + f0 + l15] = val;
    }
}

// ---------------------------------------------------------------------------
extern "C" void kernel_launch(void* const* d_in, const int* in_sizes, int n_in,
                              void* d_out, int out_size, void* d_ws, size_t ws_size,
                              hipStream_t stream) {
    const float* x   = (const float*)d_in[0];
    const int*   adj = (const int*)d_in[1];
    const float* W   = (const float*)d_in[2];
    const float* w2  = (const float*)d_in[3];
    float* out = (float*)d_out;

    _Float16* whT = (_Float16*)d_ws;                                  // 2 MiB
    float* s1 = (float*)((char*)d_ws + (size_t)B_ * FOUT * N_ * 2);   // 64 KiB
    float* s2 = s1 + (size_t)B_ * N_;                                 // 64 KiB
    _Float16* WtG = (_Float16*)(s2 + (size_t)B_ * N_);                // 32 KiB (hi+lo)

    k0_convW<<<32, 256, 0, stream>>>(W, WtG);
    k1_wh<<<(B_ * N_) / 32, 256, 0, stream>>>(x, WtG, w2, whT, s1, s2);
    k2_attn<<<(B_ * N_) / 16, 256, 0, stream>>>(adj, whT, s1, s2, out);
}